// Round 17
// baseline (180.361 us; speedup 1.0000x reference)
//
#include <hip/hip_runtime.h>
#include <math.h>

// Problem constants (b=8, c=2048, e=64, h=8)
#define NTOK 16384
#define EDIM 64
#define HHE  512   // h*e
#define TOKPAD 260 // half2 slots per token row: 256 + 4 pad (16B-aligned rows)

typedef _Float16 half8 __attribute__((ext_vector_type(8)));   // MFMA operand type
typedef __fp16   half2v __attribute__((ext_vector_type(2)));  // builtin V2h type
typedef _Float16 half2m __attribute__((ext_vector_type(2)));  // native fp16 math
typedef float    floatx4 __attribute__((ext_vector_type(4)));

__device__ __forceinline__ half8 cvt8(const float4 a, const float4 b) {
    half8 h;
    h[0] = (_Float16)a.x; h[1] = (_Float16)a.y;
    h[2] = (_Float16)a.z; h[3] = (_Float16)a.w;
    h[4] = (_Float16)b.x; h[5] = (_Float16)b.y;
    h[6] = (_Float16)b.z; h[7] = (_Float16)b.w;
    return h;
}

// fp32 += half2 . half2 (v_dot2_f32_f16); float fallback if builtin missing
__device__ __forceinline__ float dot2(half2v a, half2v b, float c) {
#if __has_builtin(__builtin_amdgcn_fdot2)
    return __builtin_amdgcn_fdot2(a, b, c, false);
#else
    return fmaf((float)a[0], (float)b[0], fmaf((float)a[1], (float)b[1], c));
#endif
}
__device__ __forceinline__ half2v pk(float x, float y) {
    return __builtin_amdgcn_cvt_pkrtz(x, y);   // v_cvt_pkrtz_f16_f32 (V2h)
}
union h2u  { half2v h; unsigned int u; };
union h2mu { half2m m; half2v v; unsigned int u; };

__device__ __forceinline__ half2v bc(half2m a) {   // free bit-cast m->v
    h2mu u; u.m = a; return u.v;
}
__device__ __forceinline__ half2m max2(half2m a, half2m b) {   // v_pk_max_f16
#if __has_builtin(__builtin_elementwise_max)
    return __builtin_elementwise_max(a, b);
#else
    half2m r;
    r[0] = a[0] > b[0] ? a[0] : b[0];
    r[1] = a[1] > b[1] ? a[1] : b[1];
    return r;
#endif
}

__device__ __forceinline__ float clamp01(float z) {
    return __builtin_amdgcn_fmed3f(z, 0.0f, 1.0f);   // v_med3_f32
}
__device__ __forceinline__ float pgen(float z, float inv) {
    return z > 0.0f ? exp2f(inv * log2f(fmaxf(z, 1e-30f))) : 0.0f;
}

// ---------------------------------------------------------------------------
// Kernel 0: one-shot fp32 -> fp16 (RTN cast) for x + all W. (R16, unchanged)
// ---------------------------------------------------------------------------
__global__ __launch_bounds__(256) void cvt_fp16_kernel(
    const float* __restrict__ x,
    const float* __restrict__ Wk, const float* __restrict__ Wq,
    const float* __restrict__ Wv, const float* __restrict__ Wu,
    __fp16* __restrict__ xh, __fp16* __restrict__ wkh,
    __fp16* __restrict__ wqh, __fp16* __restrict__ wvh,
    __fp16* __restrict__ wuh)
{
    const int z = blockIdx.y;
    const float* src; __fp16* dst; int n;
    if      (z == 0) { src = x;  dst = xh;  n = NTOK * EDIM; }
    else if (z == 1) { src = Wk; dst = wkh; n = HHE * EDIM; }
    else if (z == 2) { src = Wq; dst = wqh; n = HHE * EDIM; }
    else if (z == 3) { src = Wv; dst = wvh; n = HHE * EDIM; }
    else             { src = Wu; dst = wuh; n = EDIM * HHE; }
    const int idx = (blockIdx.x * 256 + threadIdx.x) * 8;
    if (idx < n) {
        const float4 a = *(const float4*)(src + idx);
        const float4 b = *(const float4*)(src + idx + 4);
        *(half8*)(dst + idx) = cvt8(a, b);
    }
}

// ---------------------------------------------------------------------------
// Kernel 1: FUSED qkv + entmax-attention. Block = 16 tokens, 4 waves.
// R16 structure; R17 change: PACKED-FP16 f-evaluation in the bisection /
// Newton / final passes. Scores live as 32 half2 regs; each pass is
// pk_sub + pk_max(0) + v_dot2_f32_f16 per PAIR (fp32 accumulation) —
// ~half the VALU inst of the scalar fp32 version. mx is computed from the
// PACKED values so the one-hot invariant (max elem -> zc = 1 exactly,
// f_lo >= 0) is preserved; tau is fp16-quantized per eval (bisection
// stalls harmlessly once dm < ulp; guarded Newton absorbs ulp overshoot;
// p-err <= ~1e-3 vs 4.28e-2 threshold).
// ---------------------------------------------------------------------------
__global__ __launch_bounds__(256) void qkv_attn_kernel(
    const __fp16* __restrict__ xh,
    const __fp16* __restrict__ wkh, const float* __restrict__ bk,
    const __fp16* __restrict__ wqh, const float* __restrict__ bq,
    const __fp16* __restrict__ wvh, const float* __restrict__ bv,
    __fp16* __restrict__ resb, const float* alpha_p)
{
    __shared__ __align__(16) half2v qT[16 * TOKPAD];  // [tok][i*4 + hpair]
    __shared__ __align__(16) half2v kT[16 * TOKPAD];  // [tok][j*4 + hpair]
    __shared__ __align__(16) half2v vT[16 * TOKPAD];  // [tok][h*32 + jpair]

    const int tid  = threadIdx.x;
    const int lane = tid & 63;
    const int w    = tid >> 6;
    const int tok0 = blockIdx.x * 16;

    const int m    = lane & 15;            // token (B row)
    const int quad = lane >> 4;

    // ---- x B-fragments (direct fp16), shared by this wave's 3 units
    const __fp16* xrow = xh + (size_t)(tok0 + m) * EDIM + quad * 8;
    half8 bfr[2];
    bfr[0] = *(const half8*)(xrow);
    bfr[1] = *(const half8*)(xrow + 32);

    // ---- producer: units w*3 .. w*3+2; unit = z*4 + ntile
    #pragma unroll
    for (int uu = 0; uu < 3; ++uu) {
        const int unit = w * 3 + uu;
        const int z    = unit >> 2;            // 0=k, 1=q, 2=v
        const int col0 = (unit & 3) * 128;
        const __fp16* W   = (z == 0) ? wkh : (z == 1) ? wqh : wvh;
        const float* bias = (z == 0) ? bk : (z == 1) ? bq : bv;
        half2v* dstT      = (z == 0) ? kT : (z == 1) ? qT : vT;

        #pragma unroll
        for (int ct = 0; ct < 8; ++ct) {
            const int n = col0 + ct * 16 + m;
            // permuted W row for q/k; natural for v
            const int grow = (z < 2) ? ((n & 7) * 64 + (n >> 3)) : n;
            const __fp16* wrow = W + (size_t)grow * EDIM + quad * 8;
            floatx4 acc = (floatx4){0.f, 0.f, 0.f, 0.f};
            #pragma unroll
            for (int kc = 0; kc < 2; ++kc) {
                const half8 af = *(const half8*)(wrow + kc * 32);  // direct fp16
                acc = __builtin_amdgcn_mfma_f32_16x16x32_f16(af, bfr[kc], acc, 0, 0, 0);
            }
            // lane's 4 regs = D rows quad*4+0..3, D col = m (token)
            h2u p0, p1;
            if (z < 2) {
                // output rows g(n'): h = 4*(quad&1)+reg, j = col0/8+ct*2+(quad>>1)
                const int hbase = 4 * (quad & 1);
                const int j     = (col0 >> 3) + ct * 2 + (quad >> 1);
                float o0 = acc[0] + bias[(hbase + 0) * 64 + j];
                float o1 = acc[1] + bias[(hbase + 1) * 64 + j];
                float o2 = acc[2] + bias[(hbase + 2) * 64 + j];
                float o3 = acc[3] + bias[(hbase + 3) * 64 + j];
                p0.h = pk(o0, o1);                 // h-pair 2*(quad&1)
                p1.h = pk(o2, o3);                 // h-pair 2*(quad&1)+1
                uint2 st; st.x = p0.u; st.y = p1.u;
                *(uint2*)&dstT[m * TOKPAD + j * 4 + 2 * (quad & 1)] = st;
            } else {
                // natural: cols nn..nn+3 = v[h][jj..jj+3]
                const int nn = col0 + ct * 16 + quad * 4;
                const int h  = nn >> 6;
                const int jj = nn & 63;
                const float4 b4 = *(const float4*)&bias[nn];
                p0.h = pk(acc[0] + b4.x, acc[1] + b4.y);
                p1.h = pk(acc[2] + b4.z, acc[3] + b4.w);
                uint2 st; st.x = p0.u; st.y = p1.u;
                *(uint2*)&dstT[m * TOKPAD + h * 32 + (jj >> 1)] = st;
            }
        }
    }
    __syncthreads();   // producer (all waves write all 16 tokens) -> consumer

    const float alpha = alpha_p[0];
    const float am1   = alpha - 1.0f;
    const half2m zero2 = (half2m)(_Float16)0.0f;
    const half2m one2  = (half2m)(_Float16)1.0f;

    // ---- consumer: each wave runs 4 tokens serially
    for (int i = 0; i < 4; ++i) {
        const int t   = w * 4 + i;
        const int tok = tok0 + t;

        union { half8 h8; half2v h2[4]; } uq;
        uq.h8 = *(const half8*)&qT[t * TOKPAD + lane * 4];

        // dot rows in PAIRS -> packed scores rowh[32] (Xa scale folded in)
        const float scale = am1 * 0.125f;
        half2m rowh[32];
        #pragma unroll
        for (int jp = 0; jp < 32; ++jp) {
            union { half8 h8; half2v h2[4]; } u0, u1;
            u0.h8 = *(const half8*)&kT[t * TOKPAD + (2 * jp) * 4];
            u1.h8 = *(const half8*)&kT[t * TOKPAD + (2 * jp + 1) * 4];
            float d0 = dot2(uq.h2[0], u0.h2[0], 0.0f);
            d0 = dot2(uq.h2[1], u0.h2[1], d0);
            d0 = dot2(uq.h2[2], u0.h2[2], d0);
            d0 = dot2(uq.h2[3], u0.h2[3], d0);
            float d1 = dot2(uq.h2[0], u1.h2[0], 0.0f);
            d1 = dot2(uq.h2[1], u1.h2[1], d1);
            d1 = dot2(uq.h2[2], u1.h2[2], d1);
            d1 = dot2(uq.h2[3], u1.h2[3], d1);
            h2mu pr; pr.v = pk(d0 * scale, d1 * scale);
            rowh[jp] = pr.m;
        }

        // mx from the PACKED values (preserves one-hot f_lo >= 0 invariant)
        half2m mh = rowh[0];
        #pragma unroll
        for (int jp = 1; jp < 32; ++jp) mh = max2(mh, rowh[jp]);
        const float mx = fmaxf((float)mh[0], (float)mh[1]);

        float tau_lo = mx - 1.0f;                         // _gp(1, alpha) = 1
        const float tau_hi = mx - exp2f(-6.0f * am1);     // (1/64)^am1
        float dm = tau_hi - tau_lo;
        float inv_sum;
        half2v p2[32];

        if (am1 == 0.5f) {
            // 6 bisection steps, f >= 0 test — packed f-eval
            #pragma unroll
            for (int it = 0; it < 6; ++it) {
                dm *= 0.5f;
                const float tau_m = tau_lo + dm;
                const _Float16 tq = (_Float16)tau_m;
                const half2m t2 = (half2m)tq;
                float f0 = -1.0f, f1 = 0.0f, f2 = 0.0f, f3 = 0.0f;
                #pragma unroll
                for (int jp = 0; jp < 32; jp += 4) {
                    const half2m z0 = max2(rowh[jp+0] - t2, zero2);
                    const half2m z1 = max2(rowh[jp+1] - t2, zero2);
                    const half2m z2 = max2(rowh[jp+2] - t2, zero2);
                    const half2m z3 = max2(rowh[jp+3] - t2, zero2);
                    f0 = dot2(bc(z0), bc(z0), f0);
                    f1 = dot2(bc(z1), bc(z1), f1);
                    f2 = dot2(bc(z2), bc(z2), f2);
                    f3 = dot2(bc(z3), bc(z3), f3);
                }
                const float f = (f0 + f1) + (f2 + f3);
                tau_lo = (f >= 0.0f) ? tau_m : tau_lo;
            }
            // 3 guarded Newton steps (tau += max(f,0)/(2s)) — packed
            float tau = tau_lo;
            #pragma unroll
            for (int it = 0; it < 3; ++it) {
                const _Float16 tq = (_Float16)tau;
                const half2m t2 = (half2m)tq;
                float f0 = -1.0f, f1 = 0.0f, f2 = 0.0f, f3 = 0.0f;
                float s0 = 0.0f, s1 = 0.0f, s2 = 0.0f, s3 = 0.0f;
                #pragma unroll
                for (int jp = 0; jp < 32; jp += 4) {
                    const half2m z0 = max2(rowh[jp+0] - t2, zero2);
                    const half2m z1 = max2(rowh[jp+1] - t2, zero2);
                    const half2m z2 = max2(rowh[jp+2] - t2, zero2);
                    const half2m z3 = max2(rowh[jp+3] - t2, zero2);
                    f0 = dot2(bc(z0), bc(z0), f0);
                    f1 = dot2(bc(z1), bc(z1), f1);
                    f2 = dot2(bc(z2), bc(z2), f2);
                    f3 = dot2(bc(z3), bc(z3), f3);
                    s0 = dot2(bc(z0), bc(one2), s0);
                    s1 = dot2(bc(z1), bc(one2), s1);
                    s2 = dot2(bc(z2), bc(one2), s2);
                    s3 = dot2(bc(z3), bc(one2), s3);
                }
                const float f = (f0 + f1) + (f2 + f3);
                const float s = ((s0 + s1) + (s2 + s3)) + 1e-20f;  // s >= ~1/8
                tau = tau + fmaxf(f, 0.0f) / (s + s);
            }
            // final p (packed, unnormalized) + sum; norm folded into av
            {
                const _Float16 tq = (_Float16)tau;
                const half2m t2 = (half2m)tq;
                float s0 = 0.0f, s1 = 0.0f;
                #pragma unroll
                for (int jp = 0; jp < 32; jp += 2) {
                    const half2m z0 = max2(rowh[jp+0] - t2, zero2);
                    const half2m z1 = max2(rowh[jp+1] - t2, zero2);
                    s0 = dot2(bc(z0), bc(z0), s0);
                    s1 = dot2(bc(z1), bc(z1), s1);
                    p2[jp+0] = bc(z0 * z0);        // v_pk_mul_f16
                    p2[jp+1] = bc(z1 * z1);
                }
                inv_sum = 1.0f / (s0 + s1);
            }
        } else {
            // faithful general-alpha path (unused for alpha=1.5): unpack fp32
            float row[64];
            #pragma unroll
            for (int jp = 0; jp < 32; ++jp) {
                row[2 * jp + 0] = (float)rowh[jp][0];
                row[2 * jp + 1] = (float)rowh[jp][1];
            }
            const float inv = 1.0f / am1;
            float tau_m = tau_lo;
            float f_lo = -1.0f;
            #pragma unroll
            for (int j = 0; j < 64; ++j) f_lo += pgen(row[j] - tau_lo, inv);
            for (int it = 0; it < 30; ++it) {
                dm *= 0.5f;
                tau_m = tau_lo + dm;
                float f = -1.0f;
                #pragma unroll
                for (int j = 0; j < 64; ++j) f += pgen(row[j] - tau_m, inv);
                tau_lo = (f * f_lo >= 0.0f) ? tau_m : tau_lo;
            }
            float s = 0.0f;
            #pragma unroll
            for (int j = 0; j < 64; ++j) {
                const float pm = pgen(row[j] - tau_m, inv);
                row[j] = pm;
                s += pm;
            }
            inv_sum = 1.0f / s;
            #pragma unroll
            for (int jp = 0; jp < 32; ++jp)
                p2[jp] = pk(row[2 * jp], row[2 * jp + 1]);
        }

        // av: res[h][lane] = inv_sum * sum_j p[j] * v[h][j]  via fp16 dot2
        float acc[8];
        #pragma unroll
        for (int h = 0; h < 8; ++h) {
            float a0 = 0.0f, a1 = 0.0f;
            #pragma unroll
            for (int jc = 0; jc < 8; ++jc) {
                union { half8 h8; half2v h2[4]; } u;
                u.h8 = *(const half8*)&vT[t * TOKPAD + h * 32 + jc * 4];
                a0 = dot2(p2[jc * 4 + 0], u.h2[0], a0);
                a1 = dot2(p2[jc * 4 + 1], u.h2[1], a1);
                a0 = dot2(p2[jc * 4 + 2], u.h2[2], a0);
                a1 = dot2(p2[jc * 4 + 3], u.h2[3], a1);
            }
            acc[h] = a0 + a1;
        }
        // res stored fp16 (per-h segments are 128 B contiguous -> coalesced)
        __fp16* rp = resb + (size_t)tok * HHE;
        #pragma unroll
        for (int h = 0; h < 8; ++h) rp[h * 64 + lane] = (__fp16)(acc[h] * inv_sum);
    }
}

// ---------------------------------------------------------------------------
// Kernel 2: out = res @ Wu^T + bu  (M=16384, N=64, K=512) — MFMA, no LDS.
// R16 version, unchanged. Held constant.
// ---------------------------------------------------------------------------
__global__ __launch_bounds__(256) void out_kernel(
    const __fp16* __restrict__ resh, const __fp16* __restrict__ wuh,
    const float* __restrict__ bu, float* __restrict__ out)
{
    const int tid  = threadIdx.x;
    const int lane = tid & 63;
    const int w    = tid >> 6;
    const int m    = lane & 15;
    const int quad = lane >> 4;

    const int tok0 = blockIdx.x * 32 + (w >> 1) * 16;  // 32 tok/block, 16/wave
    const int ctb  = (w & 1) * 2;                      // ct tiles ctb, ctb+1

    floatx4 acc[2];
    acc[0] = (floatx4){0.f, 0.f, 0.f, 0.f};
    acc[1] = (floatx4){0.f, 0.f, 0.f, 0.f};

    const __fp16* rrow = resh + (size_t)(tok0 + m) * HHE + quad * 8;

    #pragma unroll
    for (int kc = 0; kc < 16; ++kc) {                  // K=512 in 32-chunks
        const half8 bf = *(const half8*)(rrow + kc * 32);   // direct fp16 load
        #pragma unroll
        for (int c = 0; c < 2; ++c) {
            const int n = (ctb + c) * 16 + m;          // out column (Wu row)
            const half8 af =
                *(const half8*)(wuh + (size_t)n * HHE + kc * 32 + quad * 8);
            acc[c] = __builtin_amdgcn_mfma_f32_16x16x32_f16(af, bf, acc[c], 0, 0, 0);
        }
    }

    const int tok = tok0 + m;
    #pragma unroll
    for (int c = 0; c < 2; ++c) {
        const int col = (ctb + c) * 16 + quad * 4;     // 4 consecutive out cols
        const float4 b4 = *(const float4*)&bu[col];
        float4 o;
        o.x = acc[c][0] + b4.x;
        o.y = acc[c][1] + b4.y;
        o.z = acc[c][2] + b4.z;
        o.w = acc[c][3] + b4.w;
        *(float4*)&out[(size_t)tok * 64 + col] = o;
    }
}

// ---------------------------------------------------------------------------
extern "C" void kernel_launch(void* const* d_in, const int* in_sizes, int n_in,
                              void* d_out, int out_size, void* d_ws, size_t ws_size,
                              hipStream_t stream)
{
    const float* x     = (const float*)d_in[0];
    const float* alpha = (const float*)d_in[1];
    const float* Wk    = (const float*)d_in[2];
    const float* bk    = (const float*)d_in[3];
    const float* Wq    = (const float*)d_in[4];
    const float* bq    = (const float*)d_in[5];
    const float* Wv    = (const float*)d_in[6];
    const float* bv    = (const float*)d_in[7];
    const float* Wu    = (const float*)d_in[8];
    const float* bu    = (const float*)d_in[9];
    float* out = (float*)d_out;

    // workspace (fp16 units): xh 1M | wkh/wqh/wvh/wuh 32768 each | resb 8M
    __fp16* xh   = (__fp16*)d_ws;
    __fp16* wkh  = xh  + (size_t)NTOK * EDIM;
    __fp16* wqh  = wkh + (size_t)HHE * EDIM;
    __fp16* wvh  = wqh + (size_t)HHE * EDIM;
    __fp16* wuh  = wvh + (size_t)HHE * EDIM;
    __fp16* resb = wuh + (size_t)EDIM * HHE;

    cvt_fp16_kernel<<<dim3(512, 5), 256, 0, stream>>>(
        x, Wk, Wq, Wv, Wu, xh, wkh, wqh, wvh, wuh);
    qkv_attn_kernel<<<NTOK / 16, 256, 0, stream>>>(
        xh, wkh, bk, wqh, bq, wvh, bv, resb, alpha);
    out_kernel<<<NTOK / 32, 256, 0, stream>>>(resb, wuh, bu, out);
}

// Round 18
// 168.225 us; speedup vs baseline: 1.0721x; 1.0721x over previous
//
#include <hip/hip_runtime.h>
#include <math.h>

// Problem constants (b=8, c=2048, e=64, h=8)
#define NTOK 16384
#define EDIM 64
#define HHE  512   // h*e
#define TOKPAD 260 // half2 slots per token row: 256 + 4 pad (16B-aligned rows)

typedef _Float16 half8 __attribute__((ext_vector_type(8)));   // MFMA operand type
typedef __fp16   half2v __attribute__((ext_vector_type(2)));  // builtin V2h type
typedef float    floatx4 __attribute__((ext_vector_type(4)));

__device__ __forceinline__ half8 cvt8(const float4 a, const float4 b) {
    half8 h;
    h[0] = (_Float16)a.x; h[1] = (_Float16)a.y;
    h[2] = (_Float16)a.z; h[3] = (_Float16)a.w;
    h[4] = (_Float16)b.x; h[5] = (_Float16)b.y;
    h[6] = (_Float16)b.z; h[7] = (_Float16)b.w;
    return h;
}

// fp32 += half2 . half2 (v_dot2_f32_f16); float fallback if builtin missing
__device__ __forceinline__ float dot2(half2v a, half2v b, float c) {
#if __has_builtin(__builtin_amdgcn_fdot2)
    return __builtin_amdgcn_fdot2(a, b, c, false);
#else
    return fmaf((float)a[0], (float)b[0], fmaf((float)a[1], (float)b[1], c));
#endif
}
__device__ __forceinline__ half2v pk(float x, float y) {
    return __builtin_amdgcn_cvt_pkrtz(x, y);   // v_cvt_pkrtz_f16_f32 (V2h)
}
union h2u { half2v h; unsigned int u; };

__device__ __forceinline__ float clamp01(float z) {
    return __builtin_amdgcn_fmed3f(z, 0.0f, 1.0f);   // v_med3_f32
}
__device__ __forceinline__ float pgen(float z, float inv) {
    return z > 0.0f ? exp2f(inv * log2f(fmaxf(z, 1e-30f))) : 0.0f;
}

// ---------------------------------------------------------------------------
// Kernel 0: one-shot fp32 -> fp16 (RTN cast) for x + all W. (R16, unchanged)
// ---------------------------------------------------------------------------
__global__ __launch_bounds__(256) void cvt_fp16_kernel(
    const float* __restrict__ x,
    const float* __restrict__ Wk, const float* __restrict__ Wq,
    const float* __restrict__ Wv, const float* __restrict__ Wu,
    __fp16* __restrict__ xh, __fp16* __restrict__ wkh,
    __fp16* __restrict__ wqh, __fp16* __restrict__ wvh,
    __fp16* __restrict__ wuh)
{
    const int z = blockIdx.y;
    const float* src; __fp16* dst; int n;
    if      (z == 0) { src = x;  dst = xh;  n = NTOK * EDIM; }
    else if (z == 1) { src = Wk; dst = wkh; n = HHE * EDIM; }
    else if (z == 2) { src = Wq; dst = wqh; n = HHE * EDIM; }
    else if (z == 3) { src = Wv; dst = wvh; n = HHE * EDIM; }
    else             { src = Wu; dst = wuh; n = EDIM * HHE; }
    const int idx = (blockIdx.x * 256 + threadIdx.x) * 8;
    if (idx < n) {
        const float4 a = *(const float4*)(src + idx);
        const float4 b = *(const float4*)(src + idx + 4);
        *(half8*)(dst + idx) = cvt8(a, b);
    }
}

// ---------------------------------------------------------------------------
// Kernel 1: FUSED qkv + entmax-attention. Block = 16 tokens, 4 waves.
// EXACT R16 structure (scalar fp32 f-eval — R17's packed-fp16 version
// raised VGPR 80->96, dropped occupancy 27->19.6%, net -9%: resident-wave
// count beats per-wave inst count here). Single change vs R16: Newton
// 3 -> 2 steps (e2 <= 32*(32*e0^2)^2 = 1.15e-6 at e0 = 0.875*2^-6 ->
// p-err ~2e-6 << 4.28e-2 threshold). One fewer 64-elem pass per token.
// ---------------------------------------------------------------------------
__global__ __launch_bounds__(256) void qkv_attn_kernel(
    const __fp16* __restrict__ xh,
    const __fp16* __restrict__ wkh, const float* __restrict__ bk,
    const __fp16* __restrict__ wqh, const float* __restrict__ bq,
    const __fp16* __restrict__ wvh, const float* __restrict__ bv,
    __fp16* __restrict__ resb, const float* alpha_p)
{
    __shared__ __align__(16) half2v qT[16 * TOKPAD];  // [tok][i*4 + hpair]
    __shared__ __align__(16) half2v kT[16 * TOKPAD];  // [tok][j*4 + hpair]
    __shared__ __align__(16) half2v vT[16 * TOKPAD];  // [tok][h*32 + jpair]

    const int tid  = threadIdx.x;
    const int lane = tid & 63;
    const int w    = tid >> 6;
    const int tok0 = blockIdx.x * 16;

    const int m    = lane & 15;            // token (B row)
    const int quad = lane >> 4;

    // ---- x B-fragments (direct fp16), shared by this wave's 3 units
    const __fp16* xrow = xh + (size_t)(tok0 + m) * EDIM + quad * 8;
    half8 bfr[2];
    bfr[0] = *(const half8*)(xrow);
    bfr[1] = *(const half8*)(xrow + 32);

    // ---- producer: units w*3 .. w*3+2; unit = z*4 + ntile
    #pragma unroll
    for (int uu = 0; uu < 3; ++uu) {
        const int unit = w * 3 + uu;
        const int z    = unit >> 2;            // 0=k, 1=q, 2=v
        const int col0 = (unit & 3) * 128;
        const __fp16* W   = (z == 0) ? wkh : (z == 1) ? wqh : wvh;
        const float* bias = (z == 0) ? bk : (z == 1) ? bq : bv;
        half2v* dstT      = (z == 0) ? kT : (z == 1) ? qT : vT;

        #pragma unroll
        for (int ct = 0; ct < 8; ++ct) {
            const int n = col0 + ct * 16 + m;
            // permuted W row for q/k; natural for v
            const int grow = (z < 2) ? ((n & 7) * 64 + (n >> 3)) : n;
            const __fp16* wrow = W + (size_t)grow * EDIM + quad * 8;
            floatx4 acc = (floatx4){0.f, 0.f, 0.f, 0.f};
            #pragma unroll
            for (int kc = 0; kc < 2; ++kc) {
                const half8 af = *(const half8*)(wrow + kc * 32);  // direct fp16
                acc = __builtin_amdgcn_mfma_f32_16x16x32_f16(af, bfr[kc], acc, 0, 0, 0);
            }
            // lane's 4 regs = D rows quad*4+0..3, D col = m (token)
            h2u p0, p1;
            if (z < 2) {
                // output rows g(n'): h = 4*(quad&1)+reg, j = col0/8+ct*2+(quad>>1)
                const int hbase = 4 * (quad & 1);
                const int j     = (col0 >> 3) + ct * 2 + (quad >> 1);
                float o0 = acc[0] + bias[(hbase + 0) * 64 + j];
                float o1 = acc[1] + bias[(hbase + 1) * 64 + j];
                float o2 = acc[2] + bias[(hbase + 2) * 64 + j];
                float o3 = acc[3] + bias[(hbase + 3) * 64 + j];
                p0.h = pk(o0, o1);                 // h-pair 2*(quad&1)
                p1.h = pk(o2, o3);                 // h-pair 2*(quad&1)+1
                uint2 st; st.x = p0.u; st.y = p1.u;
                *(uint2*)&dstT[m * TOKPAD + j * 4 + 2 * (quad & 1)] = st;
            } else {
                // natural: cols nn..nn+3 = v[h][jj..jj+3]
                const int nn = col0 + ct * 16 + quad * 4;
                const int h  = nn >> 6;
                const int jj = nn & 63;
                const float4 b4 = *(const float4*)&bias[nn];
                p0.h = pk(acc[0] + b4.x, acc[1] + b4.y);
                p1.h = pk(acc[2] + b4.z, acc[3] + b4.w);
                uint2 st; st.x = p0.u; st.y = p1.u;
                *(uint2*)&dstT[m * TOKPAD + h * 32 + (jj >> 1)] = st;
            }
        }
    }
    __syncthreads();   // producer (all waves write all 16 tokens) -> consumer

    const float alpha = alpha_p[0];
    const float am1   = alpha - 1.0f;

    // ---- consumer: each wave runs 4 tokens serially
    for (int i = 0; i < 4; ++i) {
        const int t   = w * 4 + i;
        const int tok = tok0 + t;

        union { half8 h8; half2v h2[4]; } uq;
        uq.h8 = *(const half8*)&qT[t * TOKPAD + lane * 4];

        // dot row: row[j] = sum_h q[h][lane] * k[h][j]  (4 dot2 per j)
        float row[64];
        #pragma unroll
        for (int j = 0; j < 64; ++j) {
            union { half8 h8; half2v h2[4]; } u;
            u.h8 = *(const half8*)&kT[t * TOKPAD + j * 4];   // broadcast b128
            float d = dot2(uq.h2[0], u.h2[0], 0.0f);
            d = dot2(uq.h2[1], u.h2[1], d);
            d = dot2(uq.h2[2], u.h2[2], d);
            d = dot2(uq.h2[3], u.h2[3], d);
            row[j] = d;
        }

        // Xa = dot/sqrt(e) * (alpha-1);  1/8 and am1 fold exactly (pow-of-2)
        const float scale = am1 * 0.125f;
        #pragma unroll
        for (int j = 0; j < 64; ++j) row[j] *= scale;

        float mx = row[0];
        #pragma unroll
        for (int j = 1; j < 64; ++j) mx = fmaxf(mx, row[j]);

        float tau_lo = mx - 1.0f;                         // _gp(1, alpha) = 1
        const float tau_hi = mx - exp2f(-6.0f * am1);     // (1/64)^am1
        float dm = tau_hi - tau_lo;
        float inv_sum;

        if (am1 == 0.5f) {
            // 6 bisection steps, f >= 0 test (f_lo >= 0 provably; one-hot-safe)
            #pragma unroll
            for (int it = 0; it < 6; ++it) {
                dm *= 0.5f;
                const float tau_m = tau_lo + dm;
                float f0 = -1.0f, f1 = 0.0f, f2 = 0.0f, f3 = 0.0f;
                #pragma unroll
                for (int j = 0; j < 64; j += 4) {
                    const float a0 = clamp01(row[j+0] - tau_m);
                    const float a1 = clamp01(row[j+1] - tau_m);
                    const float a2 = clamp01(row[j+2] - tau_m);
                    const float a3 = clamp01(row[j+3] - tau_m);
                    f0 = fmaf(a0, a0, f0); f1 = fmaf(a1, a1, f1);
                    f2 = fmaf(a2, a2, f2); f3 = fmaf(a3, a3, f3);
                }
                const float f = (f0 + f1) + (f2 + f3);
                tau_lo = (f >= 0.0f) ? tau_m : tau_lo;
            }
            // 2 guarded Newton steps (tau += max(f,0)/(2s); never moves if f<0)
            float tau = tau_lo;
            #pragma unroll
            for (int it = 0; it < 2; ++it) {
                float f0 = -1.0f, f1 = 0.0f, f2 = 0.0f, f3 = 0.0f;
                float s0 = 0.0f, s1 = 0.0f, s2 = 0.0f, s3 = 0.0f;
                #pragma unroll
                for (int j = 0; j < 64; j += 4) {
                    const float a0 = clamp01(row[j+0] - tau);
                    const float a1 = clamp01(row[j+1] - tau);
                    const float a2 = clamp01(row[j+2] - tau);
                    const float a3 = clamp01(row[j+3] - tau);
                    f0 = fmaf(a0, a0, f0); f1 = fmaf(a1, a1, f1);
                    f2 = fmaf(a2, a2, f2); f3 = fmaf(a3, a3, f3);
                    s0 += a0; s1 += a1; s2 += a2; s3 += a3;
                }
                const float f = (f0 + f1) + (f2 + f3);
                const float s = ((s0 + s1) + (s2 + s3)) + 1e-20f;  // s >= 1/8
                tau = tau + fmaxf(f, 0.0f) / (s + s);
            }
            // final p (unnormalized) + sum; normalization folded into av
            float s0 = 0.0f, s1 = 0.0f;
            #pragma unroll
            for (int j = 0; j < 64; j += 2) {
                float a0 = clamp01(row[j+0] - tau);
                float a1 = clamp01(row[j+1] - tau);
                a0 *= a0; a1 *= a1;
                row[j+0] = a0; row[j+1] = a1;
                s0 += a0; s1 += a1;
            }
            inv_sum = 1.0f / (s0 + s1);
        } else {
            // faithful general-alpha path (unused for this problem's alpha=1.5)
            const float inv = 1.0f / am1;
            float tau_m = tau_lo;
            float f_lo = -1.0f;
            #pragma unroll
            for (int j = 0; j < 64; ++j) f_lo += pgen(row[j] - tau_lo, inv);
            for (int it = 0; it < 30; ++it) {
                dm *= 0.5f;
                tau_m = tau_lo + dm;
                float f = -1.0f;
                #pragma unroll
                for (int j = 0; j < 64; ++j) f += pgen(row[j] - tau_m, inv);
                tau_lo = (f * f_lo >= 0.0f) ? tau_m : tau_lo;
            }
            float s = 0.0f;
            #pragma unroll
            for (int j = 0; j < 64; ++j) {
                const float pm = pgen(row[j] - tau_m, inv);
                row[j] = pm;
                s += pm;
            }
            inv_sum = 1.0f / s;
        }

        // av: res[h][lane] = inv_sum * sum_j p[j] * v[h][j]  via fp16 dot2
        half2v p2[32];
        #pragma unroll
        for (int ii = 0; ii < 32; ++ii) p2[ii] = pk(row[2 * ii], row[2 * ii + 1]);

        float acc[8];
        #pragma unroll
        for (int h = 0; h < 8; ++h) {
            float a0 = 0.0f, a1 = 0.0f;
            #pragma unroll
            for (int jc = 0; jc < 8; ++jc) {
                union { half8 h8; half2v h2[4]; } u;
                u.h8 = *(const half8*)&vT[t * TOKPAD + h * 32 + jc * 4];
                a0 = dot2(p2[jc * 4 + 0], u.h2[0], a0);
                a1 = dot2(p2[jc * 4 + 1], u.h2[1], a1);
                a0 = dot2(p2[jc * 4 + 2], u.h2[2], a0);
                a1 = dot2(p2[jc * 4 + 3], u.h2[3], a1);
            }
            acc[h] = a0 + a1;
        }
        // res stored fp16 (per-h segments are 128 B contiguous -> coalesced)
        __fp16* rp = resb + (size_t)tok * HHE;
        #pragma unroll
        for (int h = 0; h < 8; ++h) rp[h * 64 + lane] = (__fp16)(acc[h] * inv_sum);
    }
}

// ---------------------------------------------------------------------------
// Kernel 2: out = res @ Wu^T + bu  (M=16384, N=64, K=512) — MFMA, no LDS.
// R16 version, unchanged. Held constant.
// ---------------------------------------------------------------------------
__global__ __launch_bounds__(256) void out_kernel(
    const __fp16* __restrict__ resh, const __fp16* __restrict__ wuh,
    const float* __restrict__ bu, float* __restrict__ out)
{
    const int tid  = threadIdx.x;
    const int lane = tid & 63;
    const int w    = tid >> 6;
    const int m    = lane & 15;
    const int quad = lane >> 4;

    const int tok0 = blockIdx.x * 32 + (w >> 1) * 16;  // 32 tok/block, 16/wave
    const int ctb  = (w & 1) * 2;                      // ct tiles ctb, ctb+1

    floatx4 acc[2];
    acc[0] = (floatx4){0.f, 0.f, 0.f, 0.f};
    acc[1] = (floatx4){0.f, 0.f, 0.f, 0.f};

    const __fp16* rrow = resh + (size_t)(tok0 + m) * HHE + quad * 8;

    #pragma unroll
    for (int kc = 0; kc < 16; ++kc) {                  // K=512 in 32-chunks
        const half8 bf = *(const half8*)(rrow + kc * 32);   // direct fp16 load
        #pragma unroll
        for (int c = 0; c < 2; ++c) {
            const int n = (ctb + c) * 16 + m;          // out column (Wu row)
            const half8 af =
                *(const half8*)(wuh + (size_t)n * HHE + kc * 32 + quad * 8);
            acc[c] = __builtin_amdgcn_mfma_f32_16x16x32_f16(af, bf, acc[c], 0, 0, 0);
        }
    }

    const int tok = tok0 + m;
    #pragma unroll
    for (int c = 0; c < 2; ++c) {
        const int col = (ctb + c) * 16 + quad * 4;     // 4 consecutive out cols
        const float4 b4 = *(const float4*)&bu[col];
        float4 o;
        o.x = acc[c][0] + b4.x;
        o.y = acc[c][1] + b4.y;
        o.z = acc[c][2] + b4.z;
        o.w = acc[c][3] + b4.w;
        *(float4*)&out[(size_t)tok * 64 + col] = o;
    }
}

// ---------------------------------------------------------------------------
extern "C" void kernel_launch(void* const* d_in, const int* in_sizes, int n_in,
                              void* d_out, int out_size, void* d_ws, size_t ws_size,
                              hipStream_t stream)
{
    const float* x     = (const float*)d_in[0];
    const float* alpha = (const float*)d_in[1];
    const float* Wk    = (const float*)d_in[2];
    const float* bk    = (const float*)d_in[3];
    const float* Wq    = (const float*)d_in[4];
    const float* bq    = (const float*)d_in[5];
    const float* Wv    = (const float*)d_in[6];
    const float* bv    = (const float*)d_in[7];
    const float* Wu    = (const float*)d_in[8];
    const float* bu    = (const float*)d_in[9];
    float* out = (float*)d_out;

    // workspace (fp16 units): xh 1M | wkh/wqh/wvh/wuh 32768 each | resb 8M
    __fp16* xh   = (__fp16*)d_ws;
    __fp16* wkh  = xh  + (size_t)NTOK * EDIM;
    __fp16* wqh  = wkh + (size_t)HHE * EDIM;
    __fp16* wvh  = wqh + (size_t)HHE * EDIM;
    __fp16* wuh  = wvh + (size_t)HHE * EDIM;
    __fp16* resb = wuh + (size_t)EDIM * HHE;

    cvt_fp16_kernel<<<dim3(512, 5), 256, 0, stream>>>(
        x, Wk, Wq, Wv, Wu, xh, wkh, wqh, wvh, wuh);
    qkv_attn_kernel<<<NTOK / 16, 256, 0, stream>>>(
        xh, wkh, bk, wqh, bq, wvh, bv, resb, alpha);
    out_kernel<<<NTOK / 32, 256, 0, stream>>>(resb, wuh, bu, out);
}

// Round 19
// 155.505 us; speedup vs baseline: 1.1598x; 1.0818x over previous
//
#include <hip/hip_runtime.h>
#include <math.h>

// Problem constants (b=8, c=2048, e=64, h=8)
#define NTOK 16384
#define EDIM 64
#define HHE  512   // h*e
#define TOKPAD 260 // half2 slots per token row: 256 + 4 pad (16B-aligned rows)

typedef _Float16 half8 __attribute__((ext_vector_type(8)));   // MFMA operand type
typedef __fp16   half2v __attribute__((ext_vector_type(2)));  // builtin V2h type
typedef float    floatx4 __attribute__((ext_vector_type(4)));

__device__ __forceinline__ half8 cvt8(const float4 a, const float4 b) {
    half8 h;
    h[0] = (_Float16)a.x; h[1] = (_Float16)a.y;
    h[2] = (_Float16)a.z; h[3] = (_Float16)a.w;
    h[4] = (_Float16)b.x; h[5] = (_Float16)b.y;
    h[6] = (_Float16)b.z; h[7] = (_Float16)b.w;
    return h;
}

// fp32 += half2 . half2 (v_dot2_f32_f16); float fallback if builtin missing
__device__ __forceinline__ float dot2(half2v a, half2v b, float c) {
#if __has_builtin(__builtin_amdgcn_fdot2)
    return __builtin_amdgcn_fdot2(a, b, c, false);
#else
    return fmaf((float)a[0], (float)b[0], fmaf((float)a[1], (float)b[1], c));
#endif
}
__device__ __forceinline__ half2v pk(float x, float y) {
    return __builtin_amdgcn_cvt_pkrtz(x, y);   // v_cvt_pkrtz_f16_f32 (V2h)
}
union h2u { half2v h; unsigned int u; };

__device__ __forceinline__ float clamp01(float z) {
    return __builtin_amdgcn_fmed3f(z, 0.0f, 1.0f);   // v_med3_f32
}
__device__ __forceinline__ float pgen(float z, float inv) {
    return z > 0.0f ? exp2f(inv * log2f(fmaxf(z, 1e-30f))) : 0.0f;
}

// ---------------------------------------------------------------------------
// Kernel 0: one-shot fp32 -> fp16 (RTN cast) for x + all W. (R16, unchanged)
// ---------------------------------------------------------------------------
__global__ __launch_bounds__(256) void cvt_fp16_kernel(
    const float* __restrict__ x,
    const float* __restrict__ Wk, const float* __restrict__ Wq,
    const float* __restrict__ Wv, const float* __restrict__ Wu,
    __fp16* __restrict__ xh, __fp16* __restrict__ wkh,
    __fp16* __restrict__ wqh, __fp16* __restrict__ wvh,
    __fp16* __restrict__ wuh)
{
    const int z = blockIdx.y;
    const float* src; __fp16* dst; int n;
    if      (z == 0) { src = x;  dst = xh;  n = NTOK * EDIM; }
    else if (z == 1) { src = Wk; dst = wkh; n = HHE * EDIM; }
    else if (z == 2) { src = Wq; dst = wqh; n = HHE * EDIM; }
    else if (z == 3) { src = Wv; dst = wvh; n = HHE * EDIM; }
    else             { src = Wu; dst = wuh; n = EDIM * HHE; }
    const int idx = (blockIdx.x * 256 + threadIdx.x) * 8;
    if (idx < n) {
        const float4 a = *(const float4*)(src + idx);
        const float4 b = *(const float4*)(src + idx + 4);
        *(half8*)(dst + idx) = cvt8(a, b);
    }
}

// ---------------------------------------------------------------------------
// Kernel 1: FULLY FUSED qkv + entmax-attention + output projection.
// Block = 16 tokens, 4 waves. R18 structure with out_kernel folded in:
//  - consumer writes token t's res (fp16) into qT row t's BYTES (qT is dead
//    after that wave's one dot-load of row t; rows t = w*4+i are wave-
//    private for both the q-read and the res-write -> no cross-wave hazard,
//    no extra barrier needed for the overlay).
//  - after one barrier, wave w runs one 16-col tile of the R16 out-MFMA
//    (af = Wu half8, bf = res half8 from LDS, same kc order -> bitwise-
//    identical out). Deletes the res HBM round-trip + one dispatch.
// ---------------------------------------------------------------------------
__global__ __launch_bounds__(256) void qkv_attn_out_kernel(
    const __fp16* __restrict__ xh,
    const __fp16* __restrict__ wkh, const float* __restrict__ bk,
    const __fp16* __restrict__ wqh, const float* __restrict__ bq,
    const __fp16* __restrict__ wvh, const float* __restrict__ bv,
    const __fp16* __restrict__ wuh, const float* __restrict__ bu,
    float* __restrict__ out, const float* alpha_p)
{
    __shared__ __align__(16) half2v qT[16 * TOKPAD];  // [tok][i*4+hpair] -> res overlay
    __shared__ __align__(16) half2v kT[16 * TOKPAD];  // [tok][j*4 + hpair]
    __shared__ __align__(16) half2v vT[16 * TOKPAD];  // [tok][h*32 + jpair]

    const int tid  = threadIdx.x;
    const int lane = tid & 63;
    const int w    = tid >> 6;
    const int tok0 = blockIdx.x * 16;

    const int m    = lane & 15;            // token (B row)
    const int quad = lane >> 4;

    // ---- x B-fragments (direct fp16), shared by this wave's 3 units
    const __fp16* xrow = xh + (size_t)(tok0 + m) * EDIM + quad * 8;
    half8 bfr[2];
    bfr[0] = *(const half8*)(xrow);
    bfr[1] = *(const half8*)(xrow + 32);

    // ---- producer: units w*3 .. w*3+2; unit = z*4 + ntile
    #pragma unroll
    for (int uu = 0; uu < 3; ++uu) {
        const int unit = w * 3 + uu;
        const int z    = unit >> 2;            // 0=k, 1=q, 2=v
        const int col0 = (unit & 3) * 128;
        const __fp16* W   = (z == 0) ? wkh : (z == 1) ? wqh : wvh;
        const float* bias = (z == 0) ? bk : (z == 1) ? bq : bv;
        half2v* dstT      = (z == 0) ? kT : (z == 1) ? qT : vT;

        #pragma unroll
        for (int ct = 0; ct < 8; ++ct) {
            const int n = col0 + ct * 16 + m;
            // permuted W row for q/k; natural for v
            const int grow = (z < 2) ? ((n & 7) * 64 + (n >> 3)) : n;
            const __fp16* wrow = W + (size_t)grow * EDIM + quad * 8;
            floatx4 acc = (floatx4){0.f, 0.f, 0.f, 0.f};
            #pragma unroll
            for (int kc = 0; kc < 2; ++kc) {
                const half8 af = *(const half8*)(wrow + kc * 32);  // direct fp16
                acc = __builtin_amdgcn_mfma_f32_16x16x32_f16(af, bfr[kc], acc, 0, 0, 0);
            }
            // lane's 4 regs = D rows quad*4+0..3, D col = m (token)
            h2u p0, p1;
            if (z < 2) {
                // output rows g(n'): h = 4*(quad&1)+reg, j = col0/8+ct*2+(quad>>1)
                const int hbase = 4 * (quad & 1);
                const int j     = (col0 >> 3) + ct * 2 + (quad >> 1);
                float o0 = acc[0] + bias[(hbase + 0) * 64 + j];
                float o1 = acc[1] + bias[(hbase + 1) * 64 + j];
                float o2 = acc[2] + bias[(hbase + 2) * 64 + j];
                float o3 = acc[3] + bias[(hbase + 3) * 64 + j];
                p0.h = pk(o0, o1);                 // h-pair 2*(quad&1)
                p1.h = pk(o2, o3);                 // h-pair 2*(quad&1)+1
                uint2 st; st.x = p0.u; st.y = p1.u;
                *(uint2*)&dstT[m * TOKPAD + j * 4 + 2 * (quad & 1)] = st;
            } else {
                // natural: cols nn..nn+3 = v[h][jj..jj+3]
                const int nn = col0 + ct * 16 + quad * 4;
                const int h  = nn >> 6;
                const int jj = nn & 63;
                const float4 b4 = *(const float4*)&bias[nn];
                p0.h = pk(acc[0] + b4.x, acc[1] + b4.y);
                p1.h = pk(acc[2] + b4.z, acc[3] + b4.w);
                uint2 st; st.x = p0.u; st.y = p1.u;
                *(uint2*)&dstT[m * TOKPAD + h * 32 + (jj >> 1)] = st;
            }
        }
    }
    __syncthreads();   // producer (all waves write all 16 tokens) -> consumer

    const float alpha = alpha_p[0];
    const float am1   = alpha - 1.0f;
    __fp16* resL = (__fp16*)qT;            // res overlay: row stride 520 halves

    // ---- consumer: each wave runs 4 tokens serially
    for (int i = 0; i < 4; ++i) {
        const int t = w * 4 + i;

        union { half8 h8; half2v h2[4]; } uq;
        uq.h8 = *(const half8*)&qT[t * TOKPAD + lane * 4];  // qT row t dead after this

        // dot row: row[j] = sum_h q[h][lane] * k[h][j]  (4 dot2 per j)
        float row[64];
        #pragma unroll
        for (int j = 0; j < 64; ++j) {
            union { half8 h8; half2v h2[4]; } u;
            u.h8 = *(const half8*)&kT[t * TOKPAD + j * 4];   // broadcast b128
            float d = dot2(uq.h2[0], u.h2[0], 0.0f);
            d = dot2(uq.h2[1], u.h2[1], d);
            d = dot2(uq.h2[2], u.h2[2], d);
            d = dot2(uq.h2[3], u.h2[3], d);
            row[j] = d;
        }

        // Xa = dot/sqrt(e) * (alpha-1);  1/8 and am1 fold exactly (pow-of-2)
        const float scale = am1 * 0.125f;
        #pragma unroll
        for (int j = 0; j < 64; ++j) row[j] *= scale;

        float mx = row[0];
        #pragma unroll
        for (int j = 1; j < 64; ++j) mx = fmaxf(mx, row[j]);

        float tau_lo = mx - 1.0f;                         // _gp(1, alpha) = 1
        const float tau_hi = mx - exp2f(-6.0f * am1);     // (1/64)^am1
        float dm = tau_hi - tau_lo;
        float inv_sum;

        if (am1 == 0.5f) {
            // 6 bisection steps, f >= 0 test (f_lo >= 0 provably; one-hot-safe)
            #pragma unroll
            for (int it = 0; it < 6; ++it) {
                dm *= 0.5f;
                const float tau_m = tau_lo + dm;
                float f0 = -1.0f, f1 = 0.0f, f2 = 0.0f, f3 = 0.0f;
                #pragma unroll
                for (int j = 0; j < 64; j += 4) {
                    const float a0 = clamp01(row[j+0] - tau_m);
                    const float a1 = clamp01(row[j+1] - tau_m);
                    const float a2 = clamp01(row[j+2] - tau_m);
                    const float a3 = clamp01(row[j+3] - tau_m);
                    f0 = fmaf(a0, a0, f0); f1 = fmaf(a1, a1, f1);
                    f2 = fmaf(a2, a2, f2); f3 = fmaf(a3, a3, f3);
                }
                const float f = (f0 + f1) + (f2 + f3);
                tau_lo = (f >= 0.0f) ? tau_m : tau_lo;
            }
            // 2 guarded Newton steps (tau += max(f,0)/(2s); never moves if f<0)
            float tau = tau_lo;
            #pragma unroll
            for (int it = 0; it < 2; ++it) {
                float f0 = -1.0f, f1 = 0.0f, f2 = 0.0f, f3 = 0.0f;
                float s0 = 0.0f, s1 = 0.0f, s2 = 0.0f, s3 = 0.0f;
                #pragma unroll
                for (int j = 0; j < 64; j += 4) {
                    const float a0 = clamp01(row[j+0] - tau);
                    const float a1 = clamp01(row[j+1] - tau);
                    const float a2 = clamp01(row[j+2] - tau);
                    const float a3 = clamp01(row[j+3] - tau);
                    f0 = fmaf(a0, a0, f0); f1 = fmaf(a1, a1, f1);
                    f2 = fmaf(a2, a2, f2); f3 = fmaf(a3, a3, f3);
                    s0 += a0; s1 += a1; s2 += a2; s3 += a3;
                }
                const float f = (f0 + f1) + (f2 + f3);
                const float s = ((s0 + s1) + (s2 + s3)) + 1e-20f;  // s >= 1/8
                tau = tau + fmaxf(f, 0.0f) / (s + s);
            }
            // final p (unnormalized) + sum; normalization folded into av
            float s0 = 0.0f, s1 = 0.0f;
            #pragma unroll
            for (int j = 0; j < 64; j += 2) {
                float a0 = clamp01(row[j+0] - tau);
                float a1 = clamp01(row[j+1] - tau);
                a0 *= a0; a1 *= a1;
                row[j+0] = a0; row[j+1] = a1;
                s0 += a0; s1 += a1;
            }
            inv_sum = 1.0f / (s0 + s1);
        } else {
            // faithful general-alpha path (unused for this problem's alpha=1.5)
            const float inv = 1.0f / am1;
            float tau_m = tau_lo;
            float f_lo = -1.0f;
            #pragma unroll
            for (int j = 0; j < 64; ++j) f_lo += pgen(row[j] - tau_lo, inv);
            for (int it = 0; it < 30; ++it) {
                dm *= 0.5f;
                tau_m = tau_lo + dm;
                float f = -1.0f;
                #pragma unroll
                for (int j = 0; j < 64; ++j) f += pgen(row[j] - tau_m, inv);
                tau_lo = (f * f_lo >= 0.0f) ? tau_m : tau_lo;
            }
            float s = 0.0f;
            #pragma unroll
            for (int j = 0; j < 64; ++j) {
                const float pm = pgen(row[j] - tau_m, inv);
                row[j] = pm;
                s += pm;
            }
            inv_sum = 1.0f / s;
        }

        // av: res[h][lane] = inv_sum * sum_j p[j] * v[h][j]  via fp16 dot2
        half2v p2[32];
        #pragma unroll
        for (int ii = 0; ii < 32; ++ii) p2[ii] = pk(row[2 * ii], row[2 * ii + 1]);

        float acc[8];
        #pragma unroll
        for (int h = 0; h < 8; ++h) {
            float a0 = 0.0f, a1 = 0.0f;
            #pragma unroll
            for (int jc = 0; jc < 8; ++jc) {
                union { half8 h8; half2v h2[4]; } u;
                u.h8 = *(const half8*)&vT[t * TOKPAD + h * 32 + jc * 4];
                a0 = dot2(p2[jc * 4 + 0], u.h2[0], a0);
                a1 = dot2(p2[jc * 4 + 1], u.h2[1], a1);
                a0 = dot2(p2[jc * 4 + 2], u.h2[2], a0);
                a1 = dot2(p2[jc * 4 + 3], u.h2[3], a1);
            }
            acc[h] = a0 + a1;
        }
        // res -> LDS overlay of qT row t (wave-private row; same fp16 cast
        // as R18's global store => identical values feed the out MFMA)
        #pragma unroll
        for (int h = 0; h < 8; ++h)
            resL[t * 520 + h * 64 + lane] = (__fp16)(acc[h] * inv_sum);
    }
    __syncthreads();   // all 16 tokens' res in LDS -> out phase

    // ---- out phase: wave w computes out cols w*16..w*16+15 for 16 tokens.
    // Same math/order as R16 out_kernel (af = Wu, bf = res, kc ascending).
    {
        floatx4 oacc = (floatx4){0.f, 0.f, 0.f, 0.f};
        const __fp16* rrow = resL + (size_t)m * 520 + quad * 8;   // token m
        const __fp16* wrow = wuh + (size_t)(w * 16 + m) * HHE + quad * 8;
        #pragma unroll
        for (int kc = 0; kc < 16; ++kc) {              // K=512 in 32-chunks
            const half8 bf = *(const half8*)(rrow + kc * 32);
            const half8 af = *(const half8*)(wrow + kc * 32);
            oacc = __builtin_amdgcn_mfma_f32_16x16x32_f16(af, bf, oacc, 0, 0, 0);
        }
        const int tok = tok0 + m;
        const int col = w * 16 + quad * 4;             // 4 consecutive out cols
        const float4 b4 = *(const float4*)&bu[col];
        float4 o;
        o.x = oacc[0] + b4.x;
        o.y = oacc[1] + b4.y;
        o.z = oacc[2] + b4.z;
        o.w = oacc[3] + b4.w;
        *(float4*)&out[(size_t)tok * 64 + col] = o;
    }
}

// ---------------------------------------------------------------------------
extern "C" void kernel_launch(void* const* d_in, const int* in_sizes, int n_in,
                              void* d_out, int out_size, void* d_ws, size_t ws_size,
                              hipStream_t stream)
{
    const float* x     = (const float*)d_in[0];
    const float* alpha = (const float*)d_in[1];
    const float* Wk    = (const float*)d_in[2];
    const float* bk    = (const float*)d_in[3];
    const float* Wq    = (const float*)d_in[4];
    const float* bq    = (const float*)d_in[5];
    const float* Wv    = (const float*)d_in[6];
    const float* bv    = (const float*)d_in[7];
    const float* Wu    = (const float*)d_in[8];
    const float* bu    = (const float*)d_in[9];
    float* out = (float*)d_out;

    // workspace (fp16 units): xh 1M | wkh/wqh/wvh/wuh 32768 each
    __fp16* xh   = (__fp16*)d_ws;
    __fp16* wkh  = xh  + (size_t)NTOK * EDIM;
    __fp16* wqh  = wkh + (size_t)HHE * EDIM;
    __fp16* wvh  = wqh + (size_t)HHE * EDIM;
    __fp16* wuh  = wvh + (size_t)HHE * EDIM;

    cvt_fp16_kernel<<<dim3(512, 5), 256, 0, stream>>>(
        x, Wk, Wq, Wv, Wu, xh, wkh, wqh, wvh, wuh);
    qkv_attn_out_kernel<<<NTOK / 16, 256, 0, stream>>>(
        xh, wkh, bk, wqh, bq, wvh, bv, wuh, bu, out, alpha);
}